// Round 1
// baseline (332.537 us; speedup 1.0000x reference)
//
#include <hip/hip_runtime.h>

#define VQ_K 512
#define VQ_D 64
#define VQ_N (32 * 64 * 64)   // B*H*W = 131072
#define CH_STRIDE 4096        // H*W
#define B_STRIDE  262144      // C*H*W

// Pre-pass: squared norms of codebook rows into workspace.
__global__ void cb_sqr_kernel(const float* __restrict__ cb,
                              float* __restrict__ cbsq) {
    int k = blockIdx.x * blockDim.x + threadIdx.x;
    if (k < VQ_K) {
        float s = 0.f;
        #pragma unroll
        for (int d = 0; d < VQ_D; ++d) {
            float v = cb[k * VQ_D + d];
            s = fmaf(v, v, s);
        }
        cbsq[k] = s;
    }
}

// One thread per spatial position. x is NCHW: addr = b*B_STRIDE + c*CH_STRIDE + (h*64+w).
// Codebook accesses are wave-uniform (k, d uniform) -> scalar loads through
// the constant cache; the dot FMAs take the codebook value as the SGPR operand.
__global__ __launch_bounds__(256) void vq_argmin_kernel(
        const float* __restrict__ x,
        const float* __restrict__ cb,
        const float* __restrict__ cbsq,
        int* __restrict__ out) {
    int n = blockIdx.x * 256 + threadIdx.x;   // grid sized exactly: n < VQ_N
    int b = n >> 12;          // / 4096
    int p = n & 4095;         // h*64 + w
    const float* xb = x + b * B_STRIDE + p;

    // Load this position's 64-dim vector (coalesced across lanes per channel).
    float v[VQ_D];
    #pragma unroll
    for (int d = 0; d < VQ_D; ++d) v[d] = xb[d * CH_STRIDE];

    // ||x||^2 (added to every distance like the reference; doesn't change
    // argmin in exact math but keeps float behavior close to the ref).
    float s0 = 0.f, s1 = 0.f, s2 = 0.f, s3 = 0.f;
    #pragma unroll
    for (int d = 0; d < VQ_D; d += 4) {
        s0 = fmaf(v[d + 0], v[d + 0], s0);
        s1 = fmaf(v[d + 1], v[d + 1], s1);
        s2 = fmaf(v[d + 2], v[d + 2], s2);
        s3 = fmaf(v[d + 3], v[d + 3], s3);
    }
    float insq = (s0 + s1) + (s2 + s3);

    float best = 3.4e38f;
    int bi = 0;
    #pragma unroll 2
    for (int k = 0; k < VQ_K; ++k) {
        const float* row = cb + k * VQ_D;   // uniform address -> s_load
        float d0 = 0.f, d1 = 0.f, d2 = 0.f, d3 = 0.f;
        #pragma unroll
        for (int d = 0; d < VQ_D; d += 4) {
            d0 = fmaf(v[d + 0], row[d + 0], d0);
            d1 = fmaf(v[d + 1], row[d + 1], d1);
            d2 = fmaf(v[d + 2], row[d + 2], d2);
            d3 = fmaf(v[d + 3], row[d + 3], d3);
        }
        float dot  = (d0 + d1) + (d2 + d3);
        float dist = (insq + cbsq[k]) - 2.f * dot;
        // strict < keeps the lowest index on ties, matching np.argmin
        if (dist < best) { best = dist; bi = k; }
    }
    out[n] = bi;
}

extern "C" void kernel_launch(void* const* d_in, const int* in_sizes, int n_in,
                              void* d_out, int out_size, void* d_ws, size_t ws_size,
                              hipStream_t stream) {
    const float* x  = (const float*)d_in[0];   // [32,64,64,64] fp32
    const float* cb = (const float*)d_in[1];   // [512,64] fp32
    int* out = (int*)d_out;                    // [32,64,64] int32
    float* cbsq = (float*)d_ws;                // 512 floats scratch

    cb_sqr_kernel<<<1, VQ_K, 0, stream>>>(cb, cbsq);
    vq_argmin_kernel<<<VQ_N / 256, 256, 0, stream>>>(x, cb, cbsq, out);
}